// Round 4
// baseline (3992.965 us; speedup 1.0000x reference)
//
#include <hip/hip_runtime.h>
#include <math.h>

// Problem constants
#define DD   256      // word_embd_size
#define TTT  512      // T
#define JJJ  128      // J
#define BBB  32       // B
#define NC   1536     // 6*D combined gate columns (fwd 0..767, bwd 768..1535)
#define ROWS_ALL 36864

typedef _Float16 v2h __attribute__((ext_vector_type(2)));
typedef short short8 __attribute__((ext_vector_type(8)));
typedef float f32x4 __attribute__((ext_vector_type(4)));

#if __has_builtin(__builtin_amdgcn_fdot2)
#define FDOT2(a, b, c) __builtin_amdgcn_fdot2((a), (b), (c), false)
#else
#define FDOT2(a, b, c) ((float)(a)[0] * (float)(b)[0] + ((float)(a)[1] * (float)(b)[1] + (c)))
#endif

__device__ __forceinline__ short f2bf(float f) {
    unsigned u = __float_as_uint(f);
    unsigned r = (u + 0x7FFFu + ((u >> 16) & 1u)) >> 16;   // RNE
    return (short)r;
}

// ---------------------------------------------------------------------------
// K0: prep — token table, whhT (k-major, for gru's coalesced loader),
// biases, and Bt_bf16 = concat(wih_f, wih_b) rows in bf16 (c-major, k-contig).
// ---------------------------------------------------------------------------
__global__ __launch_bounds__(256) void prep_kernel(
    const int* __restrict__ cmnt, const int* __restrict__ src_tok, const int* __restrict__ tgt_tok,
    const float* __restrict__ wih_f, const float* __restrict__ wih_b,
    const float* __restrict__ whh_f, const float* __restrict__ whh_b,
    const float* __restrict__ bih_f, const float* __restrict__ bih_b,
    const float* __restrict__ bhh_f, const float* __restrict__ bhh_b,
    int* __restrict__ tok_all, float* __restrict__ whhT,
    float* __restrict__ bihc, float* __restrict__ bhhc, short* __restrict__ Bt)
{
    const int idx = blockIdx.x * blockDim.x + threadIdx.x;
    const int stride = gridDim.x * blockDim.x;
    for (int i = idx; i < ROWS_ALL; i += stride)
        tok_all[i] = (i < 16384) ? src_tok[i] : (i < 32768) ? tgt_tok[i - 16384] : cmnt[i - 32768];
    for (int i = idx; i < 256 * NC; i += stride) {
        const int k = i / NC, c = i % NC;
        whhT[i] = (c < 768) ? whh_f[(size_t)c * 256 + k] : whh_b[(size_t)(c - 768) * 256 + k];
    }
    for (int i = idx; i < 393216; i += stride)
        Bt[i] = f2bf(i < 196608 ? wih_f[i] : wih_b[i - 196608]);
    for (int i = idx; i < NC; i += stride) {
        bihc[i] = (i < 768) ? bih_f[i] : bih_b[i - 768];
        bhhc[i] = (i < 768) ? bhh_f[i] : bhh_b[i - 768];
    }
}

// K0b: gather token embedding rows to bf16 A matrix (nrows x 256)
__global__ __launch_bounds__(256) void gatherA_kernel(
    const int* __restrict__ tok, int row_start, int nrows,
    const float* __restrict__ emb, short* __restrict__ A)
{
    const int idx = blockIdx.x * blockDim.x + threadIdx.x;
    const int stride = gridDim.x * blockDim.x;
    const int ngroups = nrows * 64;                  // 4 elems per group
    for (int g = idx; g < ngroups; g += stride) {
        const int i = g >> 6;
        const int kq = (g & 63) << 2;
        const float4 v = *(const float4*)(emb + (size_t)tok[row_start + i] * 256 + kq);
        short4 s;
        s.x = f2bf(v.x); s.y = f2bf(v.y); s.z = f2bf(v.z); s.w = f2bf(v.w);
        *(short4*)(A + (size_t)i * 256 + kq) = s;
    }
}

// ---------------------------------------------------------------------------
// K1: gi GEMM via bf16 MFMA 16x16x32. gi[m][c] = sum_k A[m][k]*Bt[c][k] + bihc[c]
// Block 256 thr (4 waves, 2x2 wave grid), tile 128x128, frags read DIRECTLY
// from global (both operands k-contiguous 16B segments; L2/L3 serve re-reads).
// A-frag: A[m=lane&15][k=quad*8+j]; B-frag: B[k=quad*8+j][n=lane&15]=Bt[n][k];
// C/D: col=lane&15, row=quad*4+reg  [m89/m120-verified layouts]
// ---------------------------------------------------------------------------
__global__ __launch_bounds__(256) void gi_mfma(
    const short* __restrict__ A, const short* __restrict__ Bt,
    const float* __restrict__ bihc, float* __restrict__ gi)
{
    const int tid = threadIdx.x;
    const int wave = tid >> 6, lane = tid & 63;
    const int quad = lane >> 4, l16 = lane & 15;
    const int m_base = blockIdx.x * 128 + (wave & 1) * 64;
    const int n_base = blockIdx.y * 128 + (wave >> 1) * 64;

    f32x4 acc[4][4];
    #pragma unroll
    for (int i = 0; i < 4; ++i)
        #pragma unroll
        for (int j = 0; j < 4; ++j) acc[i][j] = (f32x4){0.f, 0.f, 0.f, 0.f};

    for (int k0 = 0; k0 < 256; k0 += 32) {
        short8 a[4], b[4];
        #pragma unroll
        for (int i = 0; i < 4; ++i)
            a[i] = *(const short8*)(A + (size_t)(m_base + i * 16 + l16) * 256 + k0 + quad * 8);
        #pragma unroll
        for (int j = 0; j < 4; ++j)
            b[j] = *(const short8*)(Bt + (size_t)(n_base + j * 16 + l16) * 256 + k0 + quad * 8);
        #pragma unroll
        for (int i = 0; i < 4; ++i)
            #pragma unroll
            for (int j = 0; j < 4; ++j)
                acc[i][j] = __builtin_amdgcn_mfma_f32_16x16x32_bf16(a[i], b[j], acc[i][j], 0, 0, 0);
    }

    #pragma unroll
    for (int j = 0; j < 4; ++j) {
        const int col = n_base + j * 16 + l16;
        const float bias = bihc[col];
        #pragma unroll
        for (int i = 0; i < 4; ++i) {
            const int r0 = m_base + i * 16 + quad * 4;
            #pragma unroll
            for (int reg = 0; reg < 4; ++reg)
                gi[(size_t)(r0 + reg) * NC + col] = acc[i][j][reg] + bias;
        }
    }
}

// ---------------------------------------------------------------------------
// K2: GRU recurrence — full-k per thread, ONE barrier per step.
// One block per (chain, batch-row): 256 threads, thread j owns gate col j.
// Weights: 384 packed half2 in VGPRs/AGPRs (~410 regs, 1 wave/SIMD).
// h double-buffered as half2[128] in LDS: read buf s&1, write buf (s+1)&1,
// single __syncthreads per step. No partial-reduction traffic.
// ---------------------------------------------------------------------------
__global__ __launch_bounds__(256, 1) void gru_kernel(
    const float* __restrict__ gi0, const float* __restrict__ gi1, const float* __restrict__ gi2,
    const float* __restrict__ whhT, const float* __restrict__ bhhc,
    float* __restrict__ e_src, float* __restrict__ e_tgt, float* __restrict__ e_cmnt,
    int chain_base)
{
    const int chain = chain_base + (int)(blockIdx.x >> 5);
    const int b = (int)(blockIdx.x & 31);
    const int seq = chain >> 1, dir = chain & 1;
    const int Tlen = (seq == 2) ? JJJ : TTT;
    const float* gi = (seq == 0) ? gi0 : (seq == 1) ? gi1 : gi2;
    float* e = (seq == 0) ? e_src : (seq == 1) ? e_tgt : e_cmnt;

    const int j = threadIdx.x;
    const int cb = dir * 768;

    __shared__ __align__(16) v2h h2s[2][128];

    // One-time weight load: coalesced over j from k-major whhT, packed half2.
    v2h wr2[128], wz2[128], wn2[128];
    {
        const float* wb = whhT + cb + j;
        #pragma unroll
        for (int p = 0; p < 128; ++p) {
            const float* w0 = wb + (size_t)(2 * p) * NC;
            const float* w1 = wb + (size_t)(2 * p + 1) * NC;
            v2h a, bz, c;
            a[0]  = (_Float16)w0[0];   a[1]  = (_Float16)w1[0];
            bz[0] = (_Float16)w0[256]; bz[1] = (_Float16)w1[256];
            c[0]  = (_Float16)w0[512]; c[1]  = (_Float16)w1[512];
            wr2[p] = a; wz2[p] = bz; wn2[p] = c;
        }
    }
    const float br  = bhhc[cb + j];
    const float bzb = bhhc[cb + 256 + j];
    const float bnb = bhhc[cb + 512 + j];

    float hprev = 0.f;
    if (j < 128) {
        v2h z0; z0[0] = (_Float16)0.f; z0[1] = (_Float16)0.f;
        h2s[0][j] = z0;
    }
    __syncthreads();

    const int t0i = dir ? (Tlen - 1) : 0;
    const long tstep = dir ? -1 : 1;
    const float* girow = gi + (size_t)(b * Tlen + t0i) * NC + cb;
    float* eptr = e + (size_t)(b * Tlen + t0i) * 512 + (dir << 8) + j;
    const long gstep = tstep * NC;
    const long estep = tstep * 512;

    for (int s = 0; s < Tlen; ++s) {
        // gi prefetch — issued before the dot loop, consumed after
        const float gr_ = girow[j];
        const float gz_ = girow[256 + j];
        const float gn_ = girow[512 + j];

        const v2h* hb = h2s[s & 1];
        float ar = 0.f, az = 0.f, an = 0.f;
        #pragma unroll
        for (int c = 0; c < 32; ++c) {
            union { float4 f; v2h h[4]; } U;
            U.f = *(const float4*)&hb[c * 4];       // wave-uniform → LDS broadcast
            #pragma unroll
            for (int p = 0; p < 4; ++p) {
                ar = FDOT2(wr2[c * 4 + p], U.h[p], ar);
                az = FDOT2(wz2[c * 4 + p], U.h[p], az);
                an = FDOT2(wn2[c * 4 + p], U.h[p], an);
            }
        }
        const float r = 1.f / (1.f + __expf(-(gr_ + ar + br)));
        const float z = 1.f / (1.f + __expf(-(gz_ + az + bzb)));
        const float xa = gn_ + r * (an + bnb);
        const float texp = __expf(2.f * xa);
        const float n = 1.f - 2.f / (texp + 1.f);   // tanh(xa)
        const float hnew = (1.f - z) * n + z * hprev;
        hprev = hnew;
        *eptr = hnew;
        const float hnb = __shfl_xor(hnew, 1);
        if (!(j & 1)) {
            v2h hv; hv[0] = (_Float16)hnew; hv[1] = (_Float16)hnb;
            h2s[(s + 1) & 1][j >> 1] = hv;
        }
        girow += gstep;
        eptr += estep;
        __syncthreads();                            // next-buf writes visible
    }
}

// ---------------------------------------------------------------------------
// K3: S[b,t,j] = sum_d (ctx[b,t,d]*w2[d]) * ec[b,j,d] + action[b,t]*w2[512]
// NT-GEMM per (seq,b): M=512(t) x N=128(j) x K=512. BM=BN=64, BK=16, 4x4 micro.
// Fused epilogue: per-row max over this block's j-tile -> rowmaxP[jb].
// ---------------------------------------------------------------------------
__global__ __launch_bounds__(256) void sim_gemm(
    const float* __restrict__ e_src, const float* __restrict__ e_tgt,
    const float* __restrict__ e_cmnt, const float* __restrict__ w2,
    const int* __restrict__ src_action, const int* __restrict__ tgt_action,
    float* __restrict__ S, float* __restrict__ rowmaxP)
{
    const int seq = (int)(blockIdx.z >> 5);
    const int b = (int)(blockIdx.z & 31);
    const int t0 = blockIdx.x * 64;
    const int j0 = blockIdx.y * 64;
    const float* ctx = ((seq == 0) ? e_src : e_tgt) + (size_t)b * 512 * 512;
    const float* ec = e_cmnt + (size_t)b * 128 * 512;
    const int* act = (seq == 0) ? src_action : tgt_action;

    __shared__ __align__(16) float As[16][68];
    __shared__ __align__(16) float Bs[16][68];
    const int tid = threadIdx.x;
    const int lr = tid >> 2;            // 0..63
    const int lk = (tid & 3) << 2;      // 0,4,8,12
    const int ty = tid >> 4, tx = tid & 15;
    float acc[4][4];
    #pragma unroll
    for (int i = 0; i < 4; ++i)
        #pragma unroll
        for (int q = 0; q < 4; ++q) acc[i][q] = 0.f;

    for (int k0 = 0; k0 < 512; k0 += 16) {
        const float4 w4 = *(const float4*)(w2 + k0 + lk);
        const float4 a4 = *(const float4*)(ctx + (size_t)(t0 + lr) * 512 + k0 + lk);
        const float4 b4 = *(const float4*)(ec + (size_t)(j0 + lr) * 512 + k0 + lk);
        __syncthreads();
        As[lk + 0][lr] = a4.x * w4.x; As[lk + 1][lr] = a4.y * w4.y;
        As[lk + 2][lr] = a4.z * w4.z; As[lk + 3][lr] = a4.w * w4.w;
        Bs[lk + 0][lr] = b4.x; Bs[lk + 1][lr] = b4.y;
        Bs[lk + 2][lr] = b4.z; Bs[lk + 3][lr] = b4.w;
        __syncthreads();
        #pragma unroll
        for (int kk = 0; kk < 16; ++kk) {
            const float4 av = *(const float4*)&As[kk][ty * 4];
            const float4 bv = *(const float4*)&Bs[kk][tx * 4];
            float a[4] = {av.x, av.y, av.z, av.w};
            float bb[4] = {bv.x, bv.y, bv.z, bv.w};
            #pragma unroll
            for (int i = 0; i < 4; ++i)
                #pragma unroll
                for (int q = 0; q < 4; ++q) acc[i][q] = fmaf(a[i], bb[q], acc[i][q]);
        }
    }
    const float w2a = w2[512];
    #pragma unroll
    for (int i = 0; i < 4; ++i) {
        const int t = t0 + ty * 4 + i;
        const float aterm = (float)act[b * 512 + t] * w2a;
        float4 o;
        o.x = acc[i][0] + aterm; o.y = acc[i][1] + aterm;
        o.z = acc[i][2] + aterm; o.w = acc[i][3] + aterm;
        *(float4*)(S + ((size_t)((seq * 32 + b) * 512 + t)) * 128 + j0 + tx * 4) = o;
        // fused row-max over this block's 64-wide j tile
        float m = fmaxf(fmaxf(o.x, o.y), fmaxf(o.z, o.w));
        m = fmaxf(m, __shfl_xor(m, 1));
        m = fmaxf(m, __shfl_xor(m, 2));
        m = fmaxf(m, __shfl_xor(m, 4));
        m = fmaxf(m, __shfl_xor(m, 8));
        if (tx == 0)
            rowmaxP[(size_t)blockIdx.y * 32768 + (seq * 32 + b) * 512 + t] = m;
    }
}

// K5: softmax over t (512) per (seq,b); combines the 2 j-tile max partials
__global__ __launch_bounds__(256) void softmax_kernel(const float* __restrict__ rowmaxP, float* __restrict__ bw)
{
    const int base = blockIdx.x * 512;
    const int tid = threadIdx.x;
    __shared__ float red[256];
    const float v0 = fmaxf(rowmaxP[base + tid], rowmaxP[32768 + base + tid]);
    const float v1 = fmaxf(rowmaxP[base + 256 + tid], rowmaxP[32768 + base + 256 + tid]);
    red[tid] = fmaxf(v0, v1);
    __syncthreads();
    for (int off = 128; off > 0; off >>= 1) {
        if (tid < off) red[tid] = fmaxf(red[tid], red[tid + off]);
        __syncthreads();
    }
    const float M = red[0];
    __syncthreads();
    const float e0 = __expf(v0 - M), e1 = __expf(v1 - M);
    red[tid] = e0 + e1;
    __syncthreads();
    for (int off = 128; off > 0; off >>= 1) {
        if (tid < off) red[tid] += red[tid + off];
        __syncthreads();
    }
    const float inv = 1.f / red[0];
    bw[base + tid] = e0 * inv;
    bw[base + 256 + tid] = e1 * inv;
}

// K6: outSP[c][sb*128+j] = sum_{t in chunk c} bw[sb,t] * S[sb,t,j]
__global__ __launch_bounds__(256) void weighted_kernel(
    const float* __restrict__ S, const float* __restrict__ bw, float* __restrict__ outSP)
{
    const int sb = blockIdx.x;          // seq*32 + b
    const int ch = blockIdx.y;          // t-chunk 0..7
    const int tid = threadIdx.x;
    const int j = tid & 127, half = tid >> 7;
    const float* Sb = S + (size_t)sb * 512 * 128;
    const float* w = bw + sb * 512;
    const int tb = ch * 64 + half * 32;
    float acc = 0.f;
    for (int t = tb; t < tb + 32; ++t)
        acc = fmaf(w[t], Sb[(size_t)t * 128 + j], acc);
    __shared__ float red[256];
    red[tid] = acc;
    __syncthreads();
    if (half == 0) outSP[(size_t)ch * 8192 + sb * 128 + j] = red[j] + red[128 + j];
}

// K7: sum chunk partials; write S_diff and result into d_out
__global__ __launch_bounds__(256) void final_kernel(
    const float* __restrict__ outSP, const float* __restrict__ rank_w,
    const float* __restrict__ rank_b, float* __restrict__ out)
{
    __shared__ float sArr[8192];
    const int tid = threadIdx.x;
    for (int q = tid; q < 8192; q += 256) {
        float s = 0.f;
        #pragma unroll
        for (int c = 0; c < 8; ++c) s += outSP[(size_t)c * 8192 + q];
        sArr[q] = s;
    }
    __syncthreads();
    for (int q = tid; q < 8192; q += 256) {
        const int b = q >> 8, c = q & 255;
        out[32 + q] = (c < 128) ? sArr[b * 128 + c] : sArr[4096 + b * 128 + (c - 128)];
    }
    if (tid < 32) {
        float acc = rank_b[0];
        for (int c = 0; c < 128; ++c) acc = fmaf(sArr[tid * 128 + c], rank_w[c], acc);
        for (int c = 0; c < 128; ++c) acc = fmaf(sArr[4096 + tid * 128 + c], rank_w[128 + c], acc);
        out[tid] = acc;
    }
}

// ---------------------------------------------------------------------------
extern "C" void kernel_launch(void* const* d_in, const int* in_sizes, int n_in,
                              void* d_out, int out_size, void* d_ws, size_t ws_size,
                              hipStream_t stream)
{
    const int* cmnt       = (const int*)d_in[0];
    const int* src_token  = (const int*)d_in[1];
    const int* tgt_token  = (const int*)d_in[2];
    const int* src_action = (const int*)d_in[3];
    const int* tgt_action = (const int*)d_in[4];
    const float* emb    = (const float*)d_in[5];
    const float* wih_f  = (const float*)d_in[6];
    const float* whh_f  = (const float*)d_in[7];
    const float* bih_f  = (const float*)d_in[8];
    const float* bhh_f  = (const float*)d_in[9];
    const float* wih_b  = (const float*)d_in[10];
    const float* whh_b  = (const float*)d_in[11];
    const float* bih_b  = (const float*)d_in[12];
    const float* bhh_b  = (const float*)d_in[13];
    const float* w2     = (const float*)d_in[14];
    const float* rank_w = (const float*)d_in[15];
    const float* rank_b = (const float*)d_in[16];
    float* out = (float*)d_out;

    float* ws = (float*)d_ws;
    size_t off = 0;
    int*   tok_all = (int*)(ws + off); off += 36864;
    short* Bt_bf16 = (short*)(ws + off); off += 196608;   // 1536x256 bf16
    float* whhT   = ws + off; off += 393216;
    float* bihc   = ws + off; off += 1536;
    float* bhhc   = ws + off; off += 1536;
    float* rowmaxP = ws + off; off += 65536;              // 2 x 32768
    float* bw     = ws + off; off += 32768;
    float* outSP  = ws + off; off += 65536;               // 8 x 8192
    float* e_src  = ws + off; off += 8388608;
    float* e_tgt  = ws + off; off += 8388608;
    float* e_cmnt = ws + off; off += 2097152;
    float* S      = ws + off; off += 4194304;
    float* gi     = ws + off;
    const size_t avail = ws_size / 4 - off;
    const bool planP = avail >= 56623104ULL;   // gi for all 36864 rows at once

    hipLaunchKernelGGL(prep_kernel, dim3(512), dim3(256), 0, stream,
        cmnt, src_token, tgt_token, wih_f, wih_b, whh_f, whh_b,
        bih_f, bih_b, bhh_f, bhh_b, tok_all, whhT, bihc, bhhc, Bt_bf16);

    if (planP) {
        // A_bf16 (36864x256 bf16 = 4.72M float-equiv) aliases e_src (written later by gru)
        short* A = (short*)e_src;
        hipLaunchKernelGGL(gatherA_kernel, dim3(4096), dim3(256), 0, stream,
            tok_all, 0, 36864, emb, A);
        hipLaunchKernelGGL(gi_mfma, dim3(288, 12), dim3(256), 0, stream,
            A, Bt_bf16, bihc, gi);
        hipLaunchKernelGGL(gru_kernel, dim3(192), dim3(256), 0, stream,
            gi, gi + (size_t)16384 * NC, gi + (size_t)32768 * NC,
            whhT, bhhc, e_src, e_tgt, e_cmnt, 0);
    } else {
        // Serial fallback: per-seq gi chunk; A aliases S (written later)
        short* A = (short*)S;
        const int starts[3] = {0, 16384, 32768};
        const int nrows[3]  = {16384, 16384, 4096};
        for (int sq = 0; sq < 3; ++sq) {
            hipLaunchKernelGGL(gatherA_kernel, dim3(4096), dim3(256), 0, stream,
                tok_all, starts[sq], nrows[sq], emb, A);
            hipLaunchKernelGGL(gi_mfma, dim3(nrows[sq] / 128, 12), dim3(256), 0, stream,
                A, Bt_bf16, bihc, gi);
            hipLaunchKernelGGL(gru_kernel, dim3(64), dim3(256), 0, stream,
                gi, gi, gi, whhT, bhhc, e_src, e_tgt, e_cmnt, 2 * sq);
        }
    }

    hipLaunchKernelGGL(sim_gemm, dim3(8, 2, 64), dim3(256), 0, stream,
        e_src, e_tgt, e_cmnt, w2, src_action, tgt_action, S, rowmaxP);
    hipLaunchKernelGGL(softmax_kernel, dim3(64), dim3(256), 0, stream, rowmaxP, bw);
    hipLaunchKernelGGL(weighted_kernel, dim3(64, 8), dim3(256), 0, stream, S, bw, outSP);
    hipLaunchKernelGGL(final_kernel, dim3(1), dim3(256), 0, stream, outSP, rank_w, rank_b, out);
}

// Round 5
// 1790.882 us; speedup vs baseline: 2.2296x; 2.2296x over previous
//
#include <hip/hip_runtime.h>
#include <math.h>

// Problem constants
#define DD   256      // word_embd_size
#define TTT  512      // T
#define JJJ  128      // J
#define BBB  32       // B
#define NC   1536     // 6*D combined gate columns (fwd 0..767, bwd 768..1535)
#define ROWS_ALL 36864

typedef _Float16 v2h __attribute__((ext_vector_type(2)));
typedef short short8 __attribute__((ext_vector_type(8)));
typedef float f32x4 __attribute__((ext_vector_type(4)));

#if __has_builtin(__builtin_amdgcn_fdot2)
#define FDOT2(a, b, c) __builtin_amdgcn_fdot2((a), (b), (c), false)
#else
#define FDOT2(a, b, c) ((float)(a)[0] * (float)(b)[0] + ((float)(a)[1] * (float)(b)[1] + (c)))
#endif

__device__ __forceinline__ short f2bf(float f) {
    unsigned u = __float_as_uint(f);
    unsigned r = (u + 0x7FFFu + ((u >> 16) & 1u)) >> 16;   // RNE
    return (short)r;
}

// ---------------------------------------------------------------------------
// K0: prep — token table, whhT (k-major for gru), biases, Bt bf16 (c-major)
// ---------------------------------------------------------------------------
__global__ __launch_bounds__(256) void prep_kernel(
    const int* __restrict__ cmnt, const int* __restrict__ src_tok, const int* __restrict__ tgt_tok,
    const float* __restrict__ wih_f, const float* __restrict__ wih_b,
    const float* __restrict__ whh_f, const float* __restrict__ whh_b,
    const float* __restrict__ bih_f, const float* __restrict__ bih_b,
    const float* __restrict__ bhh_f, const float* __restrict__ bhh_b,
    int* __restrict__ tok_all, float* __restrict__ whhT,
    float* __restrict__ bihc, float* __restrict__ bhhc, short* __restrict__ Bt)
{
    const int idx = blockIdx.x * blockDim.x + threadIdx.x;
    const int stride = gridDim.x * blockDim.x;
    for (int i = idx; i < ROWS_ALL; i += stride)
        tok_all[i] = (i < 16384) ? src_tok[i] : (i < 32768) ? tgt_tok[i - 16384] : cmnt[i - 32768];
    for (int i = idx; i < 256 * NC; i += stride) {
        const int k = i / NC, c = i % NC;
        whhT[i] = (c < 768) ? whh_f[(size_t)c * 256 + k] : whh_b[(size_t)(c - 768) * 256 + k];
    }
    for (int i = idx; i < 393216; i += stride)
        Bt[i] = f2bf(i < 196608 ? wih_f[i] : wih_b[i - 196608]);
    for (int i = idx; i < NC; i += stride) {
        bihc[i] = (i < 768) ? bih_f[i] : bih_b[i - 768];
        bhhc[i] = (i < 768) ? bhh_f[i] : bhh_b[i - 768];
    }
}

// K0b: gather token embedding rows to bf16 A matrix (nrows x 256)
__global__ __launch_bounds__(256) void gatherA_kernel(
    const int* __restrict__ tok, int row_start, int nrows,
    const float* __restrict__ emb, short* __restrict__ A)
{
    const int idx = blockIdx.x * blockDim.x + threadIdx.x;
    const int stride = gridDim.x * blockDim.x;
    const int ngroups = nrows * 64;                  // 4 elems per group
    for (int g = idx; g < ngroups; g += stride) {
        const int i = g >> 6;
        const int kq = (g & 63) << 2;
        const float4 v = *(const float4*)(emb + (size_t)tok[row_start + i] * 256 + kq);
        short4 s;
        s.x = f2bf(v.x); s.y = f2bf(v.y); s.z = f2bf(v.z); s.w = f2bf(v.w);
        *(short4*)(A + (size_t)i * 256 + kq) = s;
    }
}

// ---------------------------------------------------------------------------
// K1: gi GEMM via bf16 MFMA 16x16x32 with LDS-staged tiles (canonical §5).
// BM=BN=128, BK=32; 256 thr (2x2 waves of 64x64). Tiles staged coalesced
// (16 B/lane), rows padded to 40 shorts (20 words) to break bank strides.
// A-frag: A[m=l16][k=quad*8+j]; B-frag: Bt[n=l16][k=quad*8+j];
// C/D: col=l16, row=quad*4+reg  [m89-verified]
// ---------------------------------------------------------------------------
#define LP 40   // padded LDS row pitch in shorts
__global__ __launch_bounds__(256) void gi_mfma(
    const short* __restrict__ A, const short* __restrict__ Bt,
    const float* __restrict__ bihc, float* __restrict__ gi)
{
    __shared__ __align__(16) short As[128 * LP];
    __shared__ __align__(16) short Bs[128 * LP];
    const int tid = threadIdx.x;
    const int wave = tid >> 6, lane = tid & 63;
    const int quad = lane >> 4, l16 = lane & 15;
    const int m0 = blockIdx.x * 128, n0 = blockIdx.y * 128;
    const int wm = (wave & 1) * 64, wn = (wave >> 1) * 64;

    const int sr = tid >> 2;            // 0..63 (staging row)
    const int sk = (tid & 3) * 8;       // 0,8,16,24 (staging k)
    const short* ga0 = A  + (size_t)(m0 + sr) * 256 + sk;
    const short* ga1 = A  + (size_t)(m0 + sr + 64) * 256 + sk;
    const short* gb0 = Bt + (size_t)(n0 + sr) * 256 + sk;
    const short* gb1 = Bt + (size_t)(n0 + sr + 64) * 256 + sk;

    f32x4 acc[4][4];
    #pragma unroll
    for (int i = 0; i < 4; ++i)
        #pragma unroll
        for (int j = 0; j < 4; ++j) acc[i][j] = (f32x4){0.f, 0.f, 0.f, 0.f};

    for (int k0 = 0; k0 < 256; k0 += 32) {
        const short8 a0 = *(const short8*)(ga0 + k0);
        const short8 a1 = *(const short8*)(ga1 + k0);
        const short8 b0 = *(const short8*)(gb0 + k0);
        const short8 b1 = *(const short8*)(gb1 + k0);
        __syncthreads();                               // prior frag reads done
        *(short8*)&As[sr * LP + sk] = a0;
        *(short8*)&As[(sr + 64) * LP + sk] = a1;
        *(short8*)&Bs[sr * LP + sk] = b0;
        *(short8*)&Bs[(sr + 64) * LP + sk] = b1;
        __syncthreads();                               // tiles visible
        short8 af[4], bf[4];
        #pragma unroll
        for (int i = 0; i < 4; ++i)
            af[i] = *(const short8*)&As[(wm + i * 16 + l16) * LP + quad * 8];
        #pragma unroll
        for (int j = 0; j < 4; ++j)
            bf[j] = *(const short8*)&Bs[(wn + j * 16 + l16) * LP + quad * 8];
        #pragma unroll
        for (int i = 0; i < 4; ++i)
            #pragma unroll
            for (int j = 0; j < 4; ++j)
                acc[i][j] = __builtin_amdgcn_mfma_f32_16x16x32_bf16(af[i], bf[j], acc[i][j], 0, 0, 0);
    }

    #pragma unroll
    for (int j = 0; j < 4; ++j) {
        const int col = n0 + wn + j * 16 + l16;
        const float bias = bihc[col];
        #pragma unroll
        for (int i = 0; i < 4; ++i) {
            const int r0 = m0 + wm + i * 16 + quad * 4;
            #pragma unroll
            for (int reg = 0; reg < 4; ++reg)
                gi[(size_t)(r0 + reg) * NC + col] = acc[i][j][reg] + bias;
        }
    }
}

// ---------------------------------------------------------------------------
// K2: GRU recurrence — fp16-packed register-resident weights (R3-proven).
// One block per (chain, batch-row): 192 blocks x 512 threads (8 waves).
//   j = tid&255 (hidden unit), q = tid>>8 (k-half of 128).
// Thread (j,q): 192 packed half2 VGPRs; 2 waves/SIMD hide LDS latency.
// ---------------------------------------------------------------------------
__global__ __launch_bounds__(512, 2) void gru_kernel(
    const float* __restrict__ gi0, const float* __restrict__ gi1, const float* __restrict__ gi2,
    const float* __restrict__ whhT, const float* __restrict__ bhhc,
    float* __restrict__ e_src, float* __restrict__ e_tgt, float* __restrict__ e_cmnt,
    int chain_base)
{
    const int chain = chain_base + (int)(blockIdx.x >> 5);
    const int b = (int)(blockIdx.x & 31);
    const int seq = chain >> 1, dir = chain & 1;
    const int Tlen = (seq == 2) ? JJJ : TTT;
    const float* gi = (seq == 0) ? gi0 : (seq == 1) ? gi1 : gi2;
    float* e = (seq == 0) ? e_src : (seq == 1) ? e_tgt : e_cmnt;

    const int tid = threadIdx.x;
    const int j = tid & 255;
    const int q = tid >> 8;
    const int cb = dir * 768;

    __shared__ __align__(16) v2h h2s[128];
    __shared__ float parts[3][256];

    // One-time weight load: fp32 from L2, packed to half2 registers.
    v2h wr2[64], wz2[64], wn2[64];
    {
        const float* wb = whhT + (size_t)(q * 128) * NC + cb + j;
        #pragma unroll
        for (int p = 0; p < 64; ++p) {
            v2h a, bzv, c;
            a[0]   = (_Float16)wb[0];        a[1]   = (_Float16)wb[NC];
            bzv[0] = (_Float16)wb[256];      bzv[1] = (_Float16)wb[NC + 256];
            c[0]   = (_Float16)wb[512];      c[1]   = (_Float16)wb[NC + 512];
            wr2[p] = a; wz2[p] = bzv; wn2[p] = c;
            wb += 2 * NC;
        }
    }
    const float br  = bhhc[cb + j];
    const float bzb = bhhc[cb + 256 + j];
    const float bnb = bhhc[cb + 512 + j];

    float hprev = 0.f;                      // q==0 thread j owns h[j]
    if (q == 0 && (j & 1) == 0) {
        v2h z0; z0[0] = (_Float16)0.f; z0[1] = (_Float16)0.f;
        h2s[j >> 1] = z0;
    }
    __syncthreads();

    const int t0i = dir ? (Tlen - 1) : 0;
    const long tstep = dir ? -1 : 1;
    const float* girow = gi + (size_t)(b * Tlen + t0i) * NC + cb;
    float* eptr = e + (size_t)(b * Tlen + t0i) * 512 + (dir << 8) + j;
    const long gstep = tstep * NC;
    const long estep = tstep * 512;

    for (int s = 0; s < Tlen; ++s) {
        // gi prefetch (q==0 consumers) issued before the dot loop
        float gr_ = 0.f, gz_ = 0.f, gn_ = 0.f;
        if (q == 0) { gr_ = girow[j]; gz_ = girow[256 + j]; gn_ = girow[512 + j]; }

        float ar = 0.f, az = 0.f, an = 0.f;
        const v2h* hbase = &h2s[q * 64];
        #pragma unroll
        for (int c = 0; c < 16; ++c) {
            union { float4 f; v2h h[4]; } U;
            U.f = *(const float4*)&hbase[c * 4];
            #pragma unroll
            for (int p = 0; p < 4; ++p) {
                ar = FDOT2(wr2[c * 4 + p], U.h[p], ar);
                az = FDOT2(wz2[c * 4 + p], U.h[p], az);
                an = FDOT2(wn2[c * 4 + p], U.h[p], an);
            }
        }
        if (q == 1) { parts[0][j] = ar; parts[1][j] = az; parts[2][j] = an; }
        __syncthreads();                    // partials visible; all h2s reads done

        if (q == 0) {
            const float sr = ar + parts[0][j] + br;
            const float sz = az + parts[1][j] + bzb;
            const float sn = an + parts[2][j] + bnb;
            const float r = 1.f / (1.f + __expf(-(gr_ + sr)));
            const float z = 1.f / (1.f + __expf(-(gz_ + sz)));
            const float n = tanhf(gn_ + r * sn);
            const float hnew = (1.f - z) * n + z * hprev;
            hprev = hnew;
            *eptr = hnew;
            const float hnb = __shfl_xor(hnew, 1);   // neighbor j^1 (same wave)
            if ((j & 1) == 0) {
                v2h hv; hv[0] = (_Float16)hnew; hv[1] = (_Float16)hnb;
                h2s[j >> 1] = hv;
            }
        }
        girow += gstep;
        eptr += estep;
        __syncthreads();                    // h2s updated before next reads
    }
}

// ---------------------------------------------------------------------------
// K3: S[b,t,j] = sum_d (ctx[b,t,d]*w2[d]) * ec[b,j,d] + action[b,t]*w2[512]
// NT-GEMM per (seq,b): M=512(t) x N=128(j) x K=512. BM=BN=64, BK=16, 4x4 micro.
// Fused epilogue: per-row max over this block's j-tile -> rowmaxP.
// ---------------------------------------------------------------------------
__global__ __launch_bounds__(256) void sim_gemm(
    const float* __restrict__ e_src, const float* __restrict__ e_tgt,
    const float* __restrict__ e_cmnt, const float* __restrict__ w2,
    const int* __restrict__ src_action, const int* __restrict__ tgt_action,
    float* __restrict__ S, float* __restrict__ rowmaxP)
{
    const int seq = (int)(blockIdx.z >> 5);
    const int b = (int)(blockIdx.z & 31);
    const int t0 = blockIdx.x * 64;
    const int j0 = blockIdx.y * 64;
    const float* ctx = ((seq == 0) ? e_src : e_tgt) + (size_t)b * 512 * 512;
    const float* ec = e_cmnt + (size_t)b * 128 * 512;
    const int* act = (seq == 0) ? src_action : tgt_action;

    __shared__ __align__(16) float As[16][68];
    __shared__ __align__(16) float Bs[16][68];
    const int tid = threadIdx.x;
    const int lr = tid >> 2;            // 0..63
    const int lk = (tid & 3) << 2;      // 0,4,8,12
    const int ty = tid >> 4, tx = tid & 15;
    float acc[4][4];
    #pragma unroll
    for (int i = 0; i < 4; ++i)
        #pragma unroll
        for (int q = 0; q < 4; ++q) acc[i][q] = 0.f;

    for (int k0 = 0; k0 < 512; k0 += 16) {
        const float4 w4 = *(const float4*)(w2 + k0 + lk);
        const float4 a4 = *(const float4*)(ctx + (size_t)(t0 + lr) * 512 + k0 + lk);
        const float4 b4 = *(const float4*)(ec + (size_t)(j0 + lr) * 512 + k0 + lk);
        __syncthreads();
        As[lk + 0][lr] = a4.x * w4.x; As[lk + 1][lr] = a4.y * w4.y;
        As[lk + 2][lr] = a4.z * w4.z; As[lk + 3][lr] = a4.w * w4.w;
        Bs[lk + 0][lr] = b4.x; Bs[lk + 1][lr] = b4.y;
        Bs[lk + 2][lr] = b4.z; Bs[lk + 3][lr] = b4.w;
        __syncthreads();
        #pragma unroll
        for (int kk = 0; kk < 16; ++kk) {
            const float4 av = *(const float4*)&As[kk][ty * 4];
            const float4 bv = *(const float4*)&Bs[kk][tx * 4];
            float a[4] = {av.x, av.y, av.z, av.w};
            float bb[4] = {bv.x, bv.y, bv.z, bv.w};
            #pragma unroll
            for (int i = 0; i < 4; ++i)
                #pragma unroll
                for (int q = 0; q < 4; ++q) acc[i][q] = fmaf(a[i], bb[q], acc[i][q]);
        }
    }
    const float w2a = w2[512];
    #pragma unroll
    for (int i = 0; i < 4; ++i) {
        const int t = t0 + ty * 4 + i;
        const float aterm = (float)act[b * 512 + t] * w2a;
        float4 o;
        o.x = acc[i][0] + aterm; o.y = acc[i][1] + aterm;
        o.z = acc[i][2] + aterm; o.w = acc[i][3] + aterm;
        *(float4*)(S + ((size_t)((seq * 32 + b) * 512 + t)) * 128 + j0 + tx * 4) = o;
        // fused row-max over this block's 64-wide j tile
        float m = fmaxf(fmaxf(o.x, o.y), fmaxf(o.z, o.w));
        m = fmaxf(m, __shfl_xor(m, 1));
        m = fmaxf(m, __shfl_xor(m, 2));
        m = fmaxf(m, __shfl_xor(m, 4));
        m = fmaxf(m, __shfl_xor(m, 8));
        if (tx == 0)
            rowmaxP[(size_t)blockIdx.y * 32768 + (seq * 32 + b) * 512 + t] = m;
    }
}

// K5: softmax over t (512) per (seq,b); combines the 2 j-tile max partials
__global__ __launch_bounds__(256) void softmax_kernel(const float* __restrict__ rowmaxP, float* __restrict__ bw)
{
    const int base = blockIdx.x * 512;
    const int tid = threadIdx.x;
    __shared__ float red[256];
    const float v0 = fmaxf(rowmaxP[base + tid], rowmaxP[32768 + base + tid]);
    const float v1 = fmaxf(rowmaxP[base + 256 + tid], rowmaxP[32768 + base + 256 + tid]);
    red[tid] = fmaxf(v0, v1);
    __syncthreads();
    for (int off = 128; off > 0; off >>= 1) {
        if (tid < off) red[tid] = fmaxf(red[tid], red[tid + off]);
        __syncthreads();
    }
    const float M = red[0];
    __syncthreads();
    const float e0 = __expf(v0 - M), e1 = __expf(v1 - M);
    red[tid] = e0 + e1;
    __syncthreads();
    for (int off = 128; off > 0; off >>= 1) {
        if (tid < off) red[tid] += red[tid + off];
        __syncthreads();
    }
    const float inv = 1.f / red[0];
    bw[base + tid] = e0 * inv;
    bw[base + 256 + tid] = e1 * inv;
}

// K6: outSP[c][sb*128+j] = sum_{t in chunk c} bw[sb,t] * S[sb,t,j]
__global__ __launch_bounds__(256) void weighted_kernel(
    const float* __restrict__ S, const float* __restrict__ bw, float* __restrict__ outSP)
{
    const int sb = blockIdx.x;          // seq*32 + b
    const int ch = blockIdx.y;          // t-chunk 0..7
    const int tid = threadIdx.x;
    const int j = tid & 127, half = tid >> 7;
    const float* Sb = S + (size_t)sb * 512 * 128;
    const float* w = bw + sb * 512;
    const int tb = ch * 64 + half * 32;
    float acc = 0.f;
    for (int t = tb; t < tb + 32; ++t)
        acc = fmaf(w[t], Sb[(size_t)t * 128 + j], acc);
    __shared__ float red[256];
    red[tid] = acc;
    __syncthreads();
    if (half == 0) outSP[(size_t)ch * 8192 + sb * 128 + j] = red[j] + red[128 + j];
}

// K7: sum chunk partials; write S_diff and result into d_out
__global__ __launch_bounds__(256) void final_kernel(
    const float* __restrict__ outSP, const float* __restrict__ rank_w,
    const float* __restrict__ rank_b, float* __restrict__ out)
{
    __shared__ float sArr[8192];
    const int tid = threadIdx.x;
    for (int q = tid; q < 8192; q += 256) {
        float s = 0.f;
        #pragma unroll
        for (int c = 0; c < 8; ++c) s += outSP[(size_t)c * 8192 + q];
        sArr[q] = s;
    }
    __syncthreads();
    for (int q = tid; q < 8192; q += 256) {
        const int b = q >> 8, c = q & 255;
        out[32 + q] = (c < 128) ? sArr[b * 128 + c] : sArr[4096 + b * 128 + (c - 128)];
    }
    if (tid < 32) {
        float acc = rank_b[0];
        for (int c = 0; c < 128; ++c) acc = fmaf(sArr[tid * 128 + c], rank_w[c], acc);
        for (int c = 0; c < 128; ++c) acc = fmaf(sArr[4096 + tid * 128 + c], rank_w[128 + c], acc);
        out[tid] = acc;
    }
}

// ---------------------------------------------------------------------------
extern "C" void kernel_launch(void* const* d_in, const int* in_sizes, int n_in,
                              void* d_out, int out_size, void* d_ws, size_t ws_size,
                              hipStream_t stream)
{
    const int* cmnt       = (const int*)d_in[0];
    const int* src_token  = (const int*)d_in[1];
    const int* tgt_token  = (const int*)d_in[2];
    const int* src_action = (const int*)d_in[3];
    const int* tgt_action = (const int*)d_in[4];
    const float* emb    = (const float*)d_in[5];
    const float* wih_f  = (const float*)d_in[6];
    const float* whh_f  = (const float*)d_in[7];
    const float* bih_f  = (const float*)d_in[8];
    const float* bhh_f  = (const float*)d_in[9];
    const float* wih_b  = (const float*)d_in[10];
    const float* whh_b  = (const float*)d_in[11];
    const float* bih_b  = (const float*)d_in[12];
    const float* bhh_b  = (const float*)d_in[13];
    const float* w2     = (const float*)d_in[14];
    const float* rank_w = (const float*)d_in[15];
    const float* rank_b = (const float*)d_in[16];
    float* out = (float*)d_out;

    float* ws = (float*)d_ws;
    size_t off = 0;
    int*   tok_all = (int*)(ws + off); off += 36864;
    short* Bt_bf16 = (short*)(ws + off); off += 196608;   // 1536x256 bf16
    float* whhT   = ws + off; off += 393216;
    float* bihc   = ws + off; off += 1536;
    float* bhhc   = ws + off; off += 1536;
    float* rowmaxP = ws + off; off += 65536;              // 2 x 32768
    float* bw     = ws + off; off += 32768;
    float* outSP  = ws + off; off += 65536;               // 8 x 8192
    float* e_src  = ws + off; off += 8388608;
    float* e_tgt  = ws + off; off += 8388608;
    float* e_cmnt = ws + off; off += 2097152;
    float* S      = ws + off; off += 4194304;
    float* gi     = ws + off;
    const size_t avail = ws_size / 4 - off;
    const bool planP = avail >= 56623104ULL;   // gi for all 36864 rows at once

    hipLaunchKernelGGL(prep_kernel, dim3(512), dim3(256), 0, stream,
        cmnt, src_token, tgt_token, wih_f, wih_b, whh_f, whh_b,
        bih_f, bih_b, bhh_f, bhh_b, tok_all, whhT, bihc, bhhc, Bt_bf16);

    if (planP) {
        // A_bf16 (36864x256 bf16) aliases e_src (written later by gru)
        short* A = (short*)e_src;
        hipLaunchKernelGGL(gatherA_kernel, dim3(4096), dim3(256), 0, stream,
            tok_all, 0, 36864, emb, A);
        hipLaunchKernelGGL(gi_mfma, dim3(288, 12), dim3(256), 0, stream,
            A, Bt_bf16, bihc, gi);
        hipLaunchKernelGGL(gru_kernel, dim3(192), dim3(512), 0, stream,
            gi, gi + (size_t)16384 * NC, gi + (size_t)32768 * NC,
            whhT, bhhc, e_src, e_tgt, e_cmnt, 0);
    } else {
        // Serial fallback: per-seq gi chunk; A aliases S (written later)
        short* A = (short*)S;
        const int starts[3] = {0, 16384, 32768};
        const int nrows[3]  = {16384, 16384, 4096};
        for (int sq = 0; sq < 3; ++sq) {
            hipLaunchKernelGGL(gatherA_kernel, dim3(4096), dim3(256), 0, stream,
                tok_all, starts[sq], nrows[sq], emb, A);
            hipLaunchKernelGGL(gi_mfma, dim3(nrows[sq] / 128, 12), dim3(256), 0, stream,
                A, Bt_bf16, bihc, gi);
            hipLaunchKernelGGL(gru_kernel, dim3(64), dim3(512), 0, stream,
                gi, gi, gi, whhT, bhhc, e_src, e_tgt, e_cmnt, 2 * sq);
        }
    }

    hipLaunchKernelGGL(sim_gemm, dim3(8, 2, 64), dim3(256), 0, stream,
        e_src, e_tgt, e_cmnt, w2, src_action, tgt_action, S, rowmaxP);
    hipLaunchKernelGGL(softmax_kernel, dim3(64), dim3(256), 0, stream, rowmaxP, bw);
    hipLaunchKernelGGL(weighted_kernel, dim3(64, 8), dim3(256), 0, stream, S, bw, outSP);
    hipLaunchKernelGGL(final_kernel, dim3(1), dim3(256), 0, stream, outSP, rank_w, rank_b, out);
}

// Round 6
// 895.757 us; speedup vs baseline: 4.4576x; 1.9993x over previous
//
#include <hip/hip_runtime.h>
#include <math.h>

// Problem constants
#define DD   256      // word_embd_size
#define TTT  512      // T
#define JJJ  128      // J
#define BBB  32       // B
#define NC   1536     // 6*D combined gate columns (fwd 0..767, bwd 768..1535)
#define ROWS_ALL 36864

typedef _Float16 v2h __attribute__((ext_vector_type(2)));
typedef _Float16 v4h __attribute__((ext_vector_type(4)));
typedef short short8 __attribute__((ext_vector_type(8)));
typedef float f32x4 __attribute__((ext_vector_type(4)));

#if __has_builtin(__builtin_amdgcn_fdot2)
#define FDOT2(a, b, c) __builtin_amdgcn_fdot2((a), (b), (c), false)
#else
#define FDOT2(a, b, c) ((float)(a)[0] * (float)(b)[0] + ((float)(a)[1] * (float)(b)[1] + (c)))
#endif

__device__ __forceinline__ short f2bf(float f) {
    unsigned u = __float_as_uint(f);
    unsigned r = (u + 0x7FFFu + ((u >> 16) & 1u)) >> 16;   // RNE
    return (short)r;
}

// ---------------------------------------------------------------------------
// K0: prep — token table, whhT (k-major for gru), biases, Bt bf16 (c-major)
// ---------------------------------------------------------------------------
__global__ __launch_bounds__(256) void prep_kernel(
    const int* __restrict__ cmnt, const int* __restrict__ src_tok, const int* __restrict__ tgt_tok,
    const float* __restrict__ wih_f, const float* __restrict__ wih_b,
    const float* __restrict__ whh_f, const float* __restrict__ whh_b,
    const float* __restrict__ bih_f, const float* __restrict__ bih_b,
    const float* __restrict__ bhh_f, const float* __restrict__ bhh_b,
    int* __restrict__ tok_all, float* __restrict__ whhT,
    float* __restrict__ bihc, float* __restrict__ bhhc, short* __restrict__ Bt)
{
    const int idx = blockIdx.x * blockDim.x + threadIdx.x;
    const int stride = gridDim.x * blockDim.x;
    for (int i = idx; i < ROWS_ALL; i += stride)
        tok_all[i] = (i < 16384) ? src_tok[i] : (i < 32768) ? tgt_tok[i - 16384] : cmnt[i - 32768];
    for (int i = idx; i < 256 * NC; i += stride) {
        const int k = i / NC, c = i % NC;
        whhT[i] = (c < 768) ? whh_f[(size_t)c * 256 + k] : whh_b[(size_t)(c - 768) * 256 + k];
    }
    for (int i = idx; i < 393216; i += stride)
        Bt[i] = f2bf(i < 196608 ? wih_f[i] : wih_b[i - 196608]);
    for (int i = idx; i < NC; i += stride) {
        bihc[i] = (i < 768) ? bih_f[i] : bih_b[i - 768];
        bhhc[i] = (i < 768) ? bhh_f[i] : bhh_b[i - 768];
    }
}

// K0b: gather token embedding rows to bf16 A matrix (nrows x 256)
__global__ __launch_bounds__(256) void gatherA_kernel(
    const int* __restrict__ tok, int row_start, int nrows,
    const float* __restrict__ emb, short* __restrict__ A)
{
    const int idx = blockIdx.x * blockDim.x + threadIdx.x;
    const int stride = gridDim.x * blockDim.x;
    const int ngroups = nrows * 64;                  // 4 elems per group
    for (int g = idx; g < ngroups; g += stride) {
        const int i = g >> 6;
        const int kq = (g & 63) << 2;
        const float4 v = *(const float4*)(emb + (size_t)tok[row_start + i] * 256 + kq);
        short4 s;
        s.x = f2bf(v.x); s.y = f2bf(v.y); s.z = f2bf(v.z); s.w = f2bf(v.w);
        *(short4*)(A + (size_t)i * 256 + kq) = s;
    }
}

// ---------------------------------------------------------------------------
// K1: gi GEMM via bf16 MFMA 16x16x32 with LDS-staged tiles; fp16 output.
// BM=BN=128, BK=32; 256 thr (2x2 waves of 64x64), padded LDS rows.
// ---------------------------------------------------------------------------
#define LP 40   // padded LDS row pitch in shorts
__global__ __launch_bounds__(256) void gi_mfma(
    const short* __restrict__ A, const short* __restrict__ Bt,
    const float* __restrict__ bihc, _Float16* __restrict__ gi)
{
    __shared__ __align__(16) short As[128 * LP];
    __shared__ __align__(16) short Bs[128 * LP];
    const int tid = threadIdx.x;
    const int wave = tid >> 6, lane = tid & 63;
    const int quad = lane >> 4, l16 = lane & 15;
    const int m0 = blockIdx.x * 128, n0 = blockIdx.y * 128;
    const int wm = (wave & 1) * 64, wn = (wave >> 1) * 64;

    const int sr = tid >> 2;            // 0..63 (staging row)
    const int sk = (tid & 3) * 8;       // 0,8,16,24 (staging k)
    const short* ga0 = A  + (size_t)(m0 + sr) * 256 + sk;
    const short* ga1 = A  + (size_t)(m0 + sr + 64) * 256 + sk;
    const short* gb0 = Bt + (size_t)(n0 + sr) * 256 + sk;
    const short* gb1 = Bt + (size_t)(n0 + sr + 64) * 256 + sk;

    f32x4 acc[4][4];
    #pragma unroll
    for (int i = 0; i < 4; ++i)
        #pragma unroll
        for (int j = 0; j < 4; ++j) acc[i][j] = (f32x4){0.f, 0.f, 0.f, 0.f};

    for (int k0 = 0; k0 < 256; k0 += 32) {
        const short8 a0 = *(const short8*)(ga0 + k0);
        const short8 a1 = *(const short8*)(ga1 + k0);
        const short8 b0 = *(const short8*)(gb0 + k0);
        const short8 b1 = *(const short8*)(gb1 + k0);
        __syncthreads();                               // prior frag reads done
        *(short8*)&As[sr * LP + sk] = a0;
        *(short8*)&As[(sr + 64) * LP + sk] = a1;
        *(short8*)&Bs[sr * LP + sk] = b0;
        *(short8*)&Bs[(sr + 64) * LP + sk] = b1;
        __syncthreads();                               // tiles visible
        short8 af[4], bf[4];
        #pragma unroll
        for (int i = 0; i < 4; ++i)
            af[i] = *(const short8*)&As[(wm + i * 16 + l16) * LP + quad * 8];
        #pragma unroll
        for (int j = 0; j < 4; ++j)
            bf[j] = *(const short8*)&Bs[(wn + j * 16 + l16) * LP + quad * 8];
        #pragma unroll
        for (int i = 0; i < 4; ++i)
            #pragma unroll
            for (int j = 0; j < 4; ++j)
                acc[i][j] = __builtin_amdgcn_mfma_f32_16x16x32_bf16(af[i], bf[j], acc[i][j], 0, 0, 0);
    }

    #pragma unroll
    for (int j = 0; j < 4; ++j) {
        const int col = n0 + wn + j * 16 + l16;
        const float bias = bihc[col];
        #pragma unroll
        for (int i = 0; i < 4; ++i) {
            const int r0 = m0 + wm + i * 16 + quad * 4;
            #pragma unroll
            for (int reg = 0; reg < 4; ++reg)
                gi[(size_t)(r0 + reg) * NC + col] = (_Float16)(acc[i][j][reg] + bias);
        }
    }
}

// ---------------------------------------------------------------------------
// K2: GRU recurrence — fp16-packed register-resident weights (R3-proven).
// 192 blocks x 512 threads (8 waves); j = tid&255, q = tid>>8 (k-half).
// gi read fp16; e written fp16 (same rounding as the h2s recurrence state).
// ---------------------------------------------------------------------------
__global__ __launch_bounds__(512, 2) void gru_kernel(
    const _Float16* __restrict__ gi0, const _Float16* __restrict__ gi1, const _Float16* __restrict__ gi2,
    const float* __restrict__ whhT, const float* __restrict__ bhhc,
    _Float16* __restrict__ e_src, _Float16* __restrict__ e_tgt, _Float16* __restrict__ e_cmnt,
    int chain_base)
{
    const int chain = chain_base + (int)(blockIdx.x >> 5);
    const int b = (int)(blockIdx.x & 31);
    const int seq = chain >> 1, dir = chain & 1;
    const int Tlen = (seq == 2) ? JJJ : TTT;
    const _Float16* gi = (seq == 0) ? gi0 : (seq == 1) ? gi1 : gi2;
    _Float16* e = (seq == 0) ? e_src : (seq == 1) ? e_tgt : e_cmnt;

    const int tid = threadIdx.x;
    const int j = tid & 255;
    const int q = tid >> 8;
    const int cb = dir * 768;

    __shared__ __align__(16) v2h h2s[128];
    __shared__ float parts[3][256];

    // One-time weight load: fp32 from L2, packed to half2 registers.
    v2h wr2[64], wz2[64], wn2[64];
    {
        const float* wb = whhT + (size_t)(q * 128) * NC + cb + j;
        #pragma unroll
        for (int p = 0; p < 64; ++p) {
            v2h a, bzv, c;
            a[0]   = (_Float16)wb[0];        a[1]   = (_Float16)wb[NC];
            bzv[0] = (_Float16)wb[256];      bzv[1] = (_Float16)wb[NC + 256];
            c[0]   = (_Float16)wb[512];      c[1]   = (_Float16)wb[NC + 512];
            wr2[p] = a; wz2[p] = bzv; wn2[p] = c;
            wb += 2 * NC;
        }
    }
    const float br  = bhhc[cb + j];
    const float bzb = bhhc[cb + 256 + j];
    const float bnb = bhhc[cb + 512 + j];

    float hprev = 0.f;                      // q==0 thread j owns h[j]
    if (q == 0 && (j & 1) == 0) {
        v2h z0; z0[0] = (_Float16)0.f; z0[1] = (_Float16)0.f;
        h2s[j >> 1] = z0;
    }
    __syncthreads();

    const int t0i = dir ? (Tlen - 1) : 0;
    const long tstep = dir ? -1 : 1;
    const _Float16* girow = gi + (size_t)(b * Tlen + t0i) * NC + cb;
    _Float16* eptr = e + (size_t)(b * Tlen + t0i) * 512 + (dir << 8) + j;
    const long gstep = tstep * NC;
    const long estep = tstep * 512;

    for (int s = 0; s < Tlen; ++s) {
        // gi prefetch (q==0 consumers) issued before the dot loop
        float gr_ = 0.f, gz_ = 0.f, gn_ = 0.f;
        if (q == 0) {
            gr_ = (float)girow[j];
            gz_ = (float)girow[256 + j];
            gn_ = (float)girow[512 + j];
        }

        float ar = 0.f, az = 0.f, an = 0.f;
        const v2h* hbase = &h2s[q * 64];
        #pragma unroll
        for (int c = 0; c < 16; ++c) {
            union { float4 f; v2h h[4]; } U;
            U.f = *(const float4*)&hbase[c * 4];
            #pragma unroll
            for (int p = 0; p < 4; ++p) {
                ar = FDOT2(wr2[c * 4 + p], U.h[p], ar);
                az = FDOT2(wz2[c * 4 + p], U.h[p], az);
                an = FDOT2(wn2[c * 4 + p], U.h[p], an);
            }
        }
        if (q == 1) { parts[0][j] = ar; parts[1][j] = az; parts[2][j] = an; }
        __syncthreads();                    // partials visible; all h2s reads done

        if (q == 0) {
            const float sr = ar + parts[0][j] + br;
            const float sz = az + parts[1][j] + bzb;
            const float sn = an + parts[2][j] + bnb;
            const float r = 1.f / (1.f + __expf(-(gr_ + sr)));
            const float z = 1.f / (1.f + __expf(-(gz_ + sz)));
            const float n = tanhf(gn_ + r * sn);
            const float hnew = (1.f - z) * n + z * hprev;
            hprev = hnew;
            *eptr = (_Float16)hnew;
            const float hnb = __shfl_xor(hnew, 1);   // neighbor j^1 (same wave)
            if ((j & 1) == 0) {
                v2h hv; hv[0] = (_Float16)hnew; hv[1] = (_Float16)hnb;
                h2s[j >> 1] = hv;
            }
        }
        girow += gstep;
        eptr += estep;
        __syncthreads();                    // h2s updated before next reads
    }
}

// ---------------------------------------------------------------------------
// K3: S[b,t,j] = sum_d (ctx[b,t,d]*w2[d]) * ec[b,j,d] + action[b,t]*w2[512]
// fp16 inputs, fp32 LDS/accumulate. BM=BN=64, BK=16, 4x4 micro.
// Fused epilogue: per-row max over this block's j-tile -> rowmaxP.
// ---------------------------------------------------------------------------
__global__ __launch_bounds__(256) void sim_gemm(
    const _Float16* __restrict__ e_src, const _Float16* __restrict__ e_tgt,
    const _Float16* __restrict__ e_cmnt, const float* __restrict__ w2,
    const int* __restrict__ src_action, const int* __restrict__ tgt_action,
    float* __restrict__ S, float* __restrict__ rowmaxP)
{
    const int seq = (int)(blockIdx.z >> 5);
    const int b = (int)(blockIdx.z & 31);
    const int t0 = blockIdx.x * 64;
    const int j0 = blockIdx.y * 64;
    const _Float16* ctx = ((seq == 0) ? e_src : e_tgt) + (size_t)b * 512 * 512;
    const _Float16* ec = e_cmnt + (size_t)b * 128 * 512;
    const int* act = (seq == 0) ? src_action : tgt_action;

    __shared__ __align__(16) float As[16][68];
    __shared__ __align__(16) float Bs[16][68];
    const int tid = threadIdx.x;
    const int lr = tid >> 2;            // 0..63
    const int lk = (tid & 3) << 2;      // 0,4,8,12
    const int ty = tid >> 4, tx = tid & 15;
    float acc[4][4];
    #pragma unroll
    for (int i = 0; i < 4; ++i)
        #pragma unroll
        for (int q = 0; q < 4; ++q) acc[i][q] = 0.f;

    for (int k0 = 0; k0 < 512; k0 += 16) {
        const float4 w4 = *(const float4*)(w2 + k0 + lk);
        const v4h a4 = *(const v4h*)(ctx + (size_t)(t0 + lr) * 512 + k0 + lk);
        const v4h b4 = *(const v4h*)(ec + (size_t)(j0 + lr) * 512 + k0 + lk);
        __syncthreads();
        As[lk + 0][lr] = (float)a4[0] * w4.x; As[lk + 1][lr] = (float)a4[1] * w4.y;
        As[lk + 2][lr] = (float)a4[2] * w4.z; As[lk + 3][lr] = (float)a4[3] * w4.w;
        Bs[lk + 0][lr] = (float)b4[0]; Bs[lk + 1][lr] = (float)b4[1];
        Bs[lk + 2][lr] = (float)b4[2]; Bs[lk + 3][lr] = (float)b4[3];
        __syncthreads();
        #pragma unroll
        for (int kk = 0; kk < 16; ++kk) {
            const float4 av = *(const float4*)&As[kk][ty * 4];
            const float4 bv = *(const float4*)&Bs[kk][tx * 4];
            float a[4] = {av.x, av.y, av.z, av.w};
            float bb[4] = {bv.x, bv.y, bv.z, bv.w};
            #pragma unroll
            for (int i = 0; i < 4; ++i)
                #pragma unroll
                for (int q = 0; q < 4; ++q) acc[i][q] = fmaf(a[i], bb[q], acc[i][q]);
        }
    }
    const float w2a = w2[512];
    #pragma unroll
    for (int i = 0; i < 4; ++i) {
        const int t = t0 + ty * 4 + i;
        const float aterm = (float)act[b * 512 + t] * w2a;
        float4 o;
        o.x = acc[i][0] + aterm; o.y = acc[i][1] + aterm;
        o.z = acc[i][2] + aterm; o.w = acc[i][3] + aterm;
        *(float4*)(S + ((size_t)((seq * 32 + b) * 512 + t)) * 128 + j0 + tx * 4) = o;
        // fused row-max over this block's 64-wide j tile
        float m = fmaxf(fmaxf(o.x, o.y), fmaxf(o.z, o.w));
        m = fmaxf(m, __shfl_xor(m, 1));
        m = fmaxf(m, __shfl_xor(m, 2));
        m = fmaxf(m, __shfl_xor(m, 4));
        m = fmaxf(m, __shfl_xor(m, 8));
        if (tx == 0)
            rowmaxP[(size_t)blockIdx.y * 32768 + (seq * 32 + b) * 512 + t] = m;
    }
}

// K5: softmax over t (512) per (seq,b); combines the 2 j-tile max partials
__global__ __launch_bounds__(256) void softmax_kernel(const float* __restrict__ rowmaxP, float* __restrict__ bw)
{
    const int base = blockIdx.x * 512;
    const int tid = threadIdx.x;
    __shared__ float red[256];
    const float v0 = fmaxf(rowmaxP[base + tid], rowmaxP[32768 + base + tid]);
    const float v1 = fmaxf(rowmaxP[base + 256 + tid], rowmaxP[32768 + base + 256 + tid]);
    red[tid] = fmaxf(v0, v1);
    __syncthreads();
    for (int off = 128; off > 0; off >>= 1) {
        if (tid < off) red[tid] = fmaxf(red[tid], red[tid + off]);
        __syncthreads();
    }
    const float M = red[0];
    __syncthreads();
    const float e0 = __expf(v0 - M), e1 = __expf(v1 - M);
    red[tid] = e0 + e1;
    __syncthreads();
    for (int off = 128; off > 0; off >>= 1) {
        if (tid < off) red[tid] += red[tid + off];
        __syncthreads();
    }
    const float inv = 1.f / red[0];
    bw[base + tid] = e0 * inv;
    bw[base + 256 + tid] = e1 * inv;
}

// K6: outSP[c][sb*128+j] = sum_{t in chunk c} bw[sb,t] * S[sb,t,j]
__global__ __launch_bounds__(256) void weighted_kernel(
    const float* __restrict__ S, const float* __restrict__ bw, float* __restrict__ outSP)
{
    const int sb = blockIdx.x;          // seq*32 + b
    const int ch = blockIdx.y;          // t-chunk 0..7
    const int tid = threadIdx.x;
    const int j = tid & 127, half = tid >> 7;
    const float* Sb = S + (size_t)sb * 512 * 128;
    const float* w = bw + sb * 512;
    const int tb = ch * 64 + half * 32;
    float acc = 0.f;
    for (int t = tb; t < tb + 32; ++t)
        acc = fmaf(w[t], Sb[(size_t)t * 128 + j], acc);
    __shared__ float red[256];
    red[tid] = acc;
    __syncthreads();
    if (half == 0) outSP[(size_t)ch * 8192 + sb * 128 + j] = red[j] + red[128 + j];
}

// K7: sum chunk partials; write S_diff and result into d_out
__global__ __launch_bounds__(256) void final_kernel(
    const float* __restrict__ outSP, const float* __restrict__ rank_w,
    const float* __restrict__ rank_b, float* __restrict__ out)
{
    __shared__ float sArr[8192];
    const int tid = threadIdx.x;
    for (int q = tid; q < 8192; q += 256) {
        float s = 0.f;
        #pragma unroll
        for (int c = 0; c < 8; ++c) s += outSP[(size_t)c * 8192 + q];
        sArr[q] = s;
    }
    __syncthreads();
    for (int q = tid; q < 8192; q += 256) {
        const int b = q >> 8, c = q & 255;
        out[32 + q] = (c < 128) ? sArr[b * 128 + c] : sArr[4096 + b * 128 + (c - 128)];
    }
    if (tid < 32) {
        float acc = rank_b[0];
        for (int c = 0; c < 128; ++c) acc = fmaf(sArr[tid * 128 + c], rank_w[c], acc);
        for (int c = 0; c < 128; ++c) acc = fmaf(sArr[4096 + tid * 128 + c], rank_w[128 + c], acc);
        out[tid] = acc;
    }
}

// ---------------------------------------------------------------------------
extern "C" void kernel_launch(void* const* d_in, const int* in_sizes, int n_in,
                              void* d_out, int out_size, void* d_ws, size_t ws_size,
                              hipStream_t stream)
{
    const int* cmnt       = (const int*)d_in[0];
    const int* src_token  = (const int*)d_in[1];
    const int* tgt_token  = (const int*)d_in[2];
    const int* src_action = (const int*)d_in[3];
    const int* tgt_action = (const int*)d_in[4];
    const float* emb    = (const float*)d_in[5];
    const float* wih_f  = (const float*)d_in[6];
    const float* whh_f  = (const float*)d_in[7];
    const float* bih_f  = (const float*)d_in[8];
    const float* bhh_f  = (const float*)d_in[9];
    const float* wih_b  = (const float*)d_in[10];
    const float* whh_b  = (const float*)d_in[11];
    const float* bih_b  = (const float*)d_in[12];
    const float* bhh_b  = (const float*)d_in[13];
    const float* w2     = (const float*)d_in[14];
    const float* rank_w = (const float*)d_in[15];
    const float* rank_b = (const float*)d_in[16];
    float* out = (float*)d_out;

    // Workspace layout (units: fp32 slots). e_* and gi are fp16 now.
    float* ws = (float*)d_ws;
    size_t off = 0;
    int*   tok_all = (int*)(ws + off); off += 36864;
    short* Bt_bf16 = (short*)(ws + off); off += 196608;       // 1536x256 bf16
    float* whhT   = ws + off; off += 393216;
    float* bihc   = ws + off; off += 1536;
    float* bhhc   = ws + off; off += 1536;
    float* rowmaxP = ws + off; off += 65536;                  // 2 x 32768
    float* bw     = ws + off; off += 32768;
    float* outSP  = ws + off; off += 65536;                   // 8 x 8192
    _Float16* e_src  = (_Float16*)(ws + off); off += 4194304; // 8.4M halfs
    _Float16* e_tgt  = (_Float16*)(ws + off); off += 4194304;
    _Float16* e_cmnt = (_Float16*)(ws + off); off += 1048576; // 2.1M halfs
    float* S      = ws + off; off += 4194304;
    _Float16* gih = (_Float16*)(ws + off);
    const size_t avail = ws_size / 4 - off;
    // Tier A: full fp16 gi (36864 x 1536 halfs = 28311552 fp32 slots) -> 171 MB total
    const bool planP = avail >= 28311552ULL;

    hipLaunchKernelGGL(prep_kernel, dim3(512), dim3(256), 0, stream,
        cmnt, src_token, tgt_token, wih_f, wih_b, whh_f, whh_b,
        bih_f, bih_b, bhh_f, bhh_b, tok_all, whhT, bihc, bhhc, Bt_bf16);

    if (planP) {
        // A_bf16 (36864x256 shorts = 18.9 MB) aliases e_src+e_tgt (33.6 MB),
        // consumed by gi_mfma before gru writes e.
        short* A = (short*)e_src;
        hipLaunchKernelGGL(gatherA_kernel, dim3(4096), dim3(256), 0, stream,
            tok_all, 0, 36864, emb, A);
        hipLaunchKernelGGL(gi_mfma, dim3(288, 12), dim3(256), 0, stream,
            A, Bt_bf16, bihc, gih);
        hipLaunchKernelGGL(gru_kernel, dim3(192), dim3(512), 0, stream,
            gih, gih + (size_t)16384 * NC, gih + (size_t)32768 * NC,
            whhT, bhhc, e_src, e_tgt, e_cmnt, 0);
    } else {
        // Serial fallback: per-seq fp16 gi chunk; A aliases S (S >= 8.4 MB)
        short* A = (short*)S;
        const int starts[3] = {0, 16384, 32768};
        const int nrows[3]  = {16384, 16384, 4096};
        for (int sq = 0; sq < 3; ++sq) {
            hipLaunchKernelGGL(gatherA_kernel, dim3(4096), dim3(256), 0, stream,
                tok_all, starts[sq], nrows[sq], emb, A);
            hipLaunchKernelGGL(gi_mfma, dim3(nrows[sq] / 128, 12), dim3(256), 0, stream,
                A, Bt_bf16, bihc, gih);
            hipLaunchKernelGGL(gru_kernel, dim3(64), dim3(512), 0, stream,
                gih, gih, gih, whhT, bhhc, e_src, e_tgt, e_cmnt, 2 * sq);
        }
    }

    hipLaunchKernelGGL(sim_gemm, dim3(8, 2, 64), dim3(256), 0, stream,
        e_src, e_tgt, e_cmnt, w2, src_action, tgt_action, S, rowmaxP);
    hipLaunchKernelGGL(softmax_kernel, dim3(64), dim3(256), 0, stream, rowmaxP, bw);
    hipLaunchKernelGGL(weighted_kernel, dim3(64, 8), dim3(256), 0, stream, S, bw, outSP);
    hipLaunchKernelGGL(final_kernel, dim3(1), dim3(256), 0, stream, outSP, rank_w, rank_b, out);
}

// Round 7
// 846.337 us; speedup vs baseline: 4.7179x; 1.0584x over previous
//
#include <hip/hip_runtime.h>
#include <math.h>

// Problem constants
#define DD   256      // word_embd_size
#define TTT  512      // T
#define JJJ  128      // J
#define BBB  32       // B
#define NC   1536     // 6*D combined gate columns (fwd 0..767, bwd 768..1535)
#define ROWS_ALL 36864

typedef _Float16 v2h __attribute__((ext_vector_type(2)));
typedef _Float16 v4h __attribute__((ext_vector_type(4)));
typedef _Float16 v8h __attribute__((ext_vector_type(8)));
typedef short short8 __attribute__((ext_vector_type(8)));
typedef float f32x4 __attribute__((ext_vector_type(4)));

#if __has_builtin(__builtin_amdgcn_fdot2)
#define FDOT2(a, b, c) __builtin_amdgcn_fdot2((a), (b), (c), false)
#else
#define FDOT2(a, b, c) ((float)(a)[0] * (float)(b)[0] + ((float)(a)[1] * (float)(b)[1] + (c)))
#endif

__device__ __forceinline__ short f2bf(float f) {
    unsigned u = __float_as_uint(f);
    unsigned r = (u + 0x7FFFu + ((u >> 16) & 1u)) >> 16;   // RNE
    return (short)r;
}

// ---------------------------------------------------------------------------
// K0: prep — token table, whhT (k-major for gru), biases, Bt bf16, w2 fp16
// ---------------------------------------------------------------------------
__global__ __launch_bounds__(256) void prep_kernel(
    const int* __restrict__ cmnt, const int* __restrict__ src_tok, const int* __restrict__ tgt_tok,
    const float* __restrict__ wih_f, const float* __restrict__ wih_b,
    const float* __restrict__ whh_f, const float* __restrict__ whh_b,
    const float* __restrict__ bih_f, const float* __restrict__ bih_b,
    const float* __restrict__ bhh_f, const float* __restrict__ bhh_b,
    const float* __restrict__ w2,
    int* __restrict__ tok_all, float* __restrict__ whhT,
    float* __restrict__ bihc, float* __restrict__ bhhc, short* __restrict__ Bt,
    _Float16* __restrict__ w2h)
{
    const int idx = blockIdx.x * blockDim.x + threadIdx.x;
    const int stride = gridDim.x * blockDim.x;
    for (int i = idx; i < ROWS_ALL; i += stride)
        tok_all[i] = (i < 16384) ? src_tok[i] : (i < 32768) ? tgt_tok[i - 16384] : cmnt[i - 32768];
    for (int i = idx; i < 256 * NC; i += stride) {
        const int k = i / NC, c = i % NC;
        whhT[i] = (c < 768) ? whh_f[(size_t)c * 256 + k] : whh_b[(size_t)(c - 768) * 256 + k];
    }
    for (int i = idx; i < 393216; i += stride)
        Bt[i] = f2bf(i < 196608 ? wih_f[i] : wih_b[i - 196608]);
    for (int i = idx; i < NC; i += stride) {
        bihc[i] = (i < 768) ? bih_f[i] : bih_b[i - 768];
        bhhc[i] = (i < 768) ? bhh_f[i] : bhh_b[i - 768];
    }
    for (int i = idx; i < 512; i += stride)
        w2h[i] = (_Float16)w2[i];
}

// K0b: gather token embedding rows to bf16 A matrix (nrows x 256)
__global__ __launch_bounds__(256) void gatherA_kernel(
    const int* __restrict__ tok, int row_start, int nrows,
    const float* __restrict__ emb, short* __restrict__ A)
{
    const int idx = blockIdx.x * blockDim.x + threadIdx.x;
    const int stride = gridDim.x * blockDim.x;
    const int ngroups = nrows * 64;                  // 4 elems per group
    for (int g = idx; g < ngroups; g += stride) {
        const int i = g >> 6;
        const int kq = (g & 63) << 2;
        const float4 v = *(const float4*)(emb + (size_t)tok[row_start + i] * 256 + kq);
        short4 s;
        s.x = f2bf(v.x); s.y = f2bf(v.y); s.z = f2bf(v.z); s.w = f2bf(v.w);
        *(short4*)(A + (size_t)i * 256 + kq) = s;
    }
}

// ---------------------------------------------------------------------------
// K1: gi GEMM via bf16 MFMA 16x16x32 with LDS-staged tiles; fp16 output.
// BM=BN=128, BK=32; 256 thr (2x2 waves of 64x64), padded LDS rows.
// ---------------------------------------------------------------------------
#define LP 40   // padded LDS row pitch in 2-byte units
__global__ __launch_bounds__(256) void gi_mfma(
    const short* __restrict__ A, const short* __restrict__ Bt,
    const float* __restrict__ bihc, _Float16* __restrict__ gi)
{
    __shared__ __align__(16) short As[128 * LP];
    __shared__ __align__(16) short Bs[128 * LP];
    const int tid = threadIdx.x;
    const int wave = tid >> 6, lane = tid & 63;
    const int quad = lane >> 4, l16 = lane & 15;
    const int m0 = blockIdx.x * 128, n0 = blockIdx.y * 128;
    const int wm = (wave & 1) * 64, wn = (wave >> 1) * 64;

    const int sr = tid >> 2;            // 0..63 (staging row)
    const int sk = (tid & 3) * 8;       // 0,8,16,24 (staging k)
    const short* ga0 = A  + (size_t)(m0 + sr) * 256 + sk;
    const short* ga1 = A  + (size_t)(m0 + sr + 64) * 256 + sk;
    const short* gb0 = Bt + (size_t)(n0 + sr) * 256 + sk;
    const short* gb1 = Bt + (size_t)(n0 + sr + 64) * 256 + sk;

    f32x4 acc[4][4];
    #pragma unroll
    for (int i = 0; i < 4; ++i)
        #pragma unroll
        for (int j = 0; j < 4; ++j) acc[i][j] = (f32x4){0.f, 0.f, 0.f, 0.f};

    for (int k0 = 0; k0 < 256; k0 += 32) {
        const short8 a0 = *(const short8*)(ga0 + k0);
        const short8 a1 = *(const short8*)(ga1 + k0);
        const short8 b0 = *(const short8*)(gb0 + k0);
        const short8 b1 = *(const short8*)(gb1 + k0);
        __syncthreads();                               // prior frag reads done
        *(short8*)&As[sr * LP + sk] = a0;
        *(short8*)&As[(sr + 64) * LP + sk] = a1;
        *(short8*)&Bs[sr * LP + sk] = b0;
        *(short8*)&Bs[(sr + 64) * LP + sk] = b1;
        __syncthreads();                               // tiles visible
        short8 af[4], bf[4];
        #pragma unroll
        for (int i = 0; i < 4; ++i)
            af[i] = *(const short8*)&As[(wm + i * 16 + l16) * LP + quad * 8];
        #pragma unroll
        for (int j = 0; j < 4; ++j)
            bf[j] = *(const short8*)&Bs[(wn + j * 16 + l16) * LP + quad * 8];
        #pragma unroll
        for (int i = 0; i < 4; ++i)
            #pragma unroll
            for (int j = 0; j < 4; ++j)
                acc[i][j] = __builtin_amdgcn_mfma_f32_16x16x32_bf16(af[i], bf[j], acc[i][j], 0, 0, 0);
    }

    #pragma unroll
    for (int j = 0; j < 4; ++j) {
        const int col = n0 + wn + j * 16 + l16;
        const float bias = bihc[col];
        #pragma unroll
        for (int i = 0; i < 4; ++i) {
            const int r0 = m0 + wm + i * 16 + quad * 4;
            #pragma unroll
            for (int reg = 0; reg < 4; ++reg)
                gi[(size_t)(r0 + reg) * NC + col] = (_Float16)(acc[i][j][reg] + bias);
        }
    }
}

// ---------------------------------------------------------------------------
// K2: GRU recurrence — fp16-packed register-resident weights.
// 192 blocks x 512 threads (8 waves); j = tid&255, q = tid>>8 (k-half).
// NEW: e-store delayed one step so the __syncthreads vmcnt(0) drain never
// exposes store latency (store issues right after a barrier, completes
// under the ~1500-cyc dot loop). tanh via inline __expf.
// ---------------------------------------------------------------------------
__global__ __launch_bounds__(512, 2) void gru_kernel(
    const _Float16* __restrict__ gi0, const _Float16* __restrict__ gi1, const _Float16* __restrict__ gi2,
    const float* __restrict__ whhT, const float* __restrict__ bhhc,
    _Float16* __restrict__ e_src, _Float16* __restrict__ e_tgt, _Float16* __restrict__ e_cmnt,
    int chain_base)
{
    const int chain = chain_base + (int)(blockIdx.x >> 5);
    const int b = (int)(blockIdx.x & 31);
    const int seq = chain >> 1, dir = chain & 1;
    const int Tlen = (seq == 2) ? JJJ : TTT;
    const _Float16* gi = (seq == 0) ? gi0 : (seq == 1) ? gi1 : gi2;
    _Float16* e = (seq == 0) ? e_src : (seq == 1) ? e_tgt : e_cmnt;

    const int tid = threadIdx.x;
    const int j = tid & 255;
    const int q = tid >> 8;
    const int cb = dir * 768;

    __shared__ __align__(16) v2h h2s[128];
    __shared__ float parts[3][256];

    // One-time weight load: fp32 from L2, packed to half2 registers.
    v2h wr2[64], wz2[64], wn2[64];
    {
        const float* wb = whhT + (size_t)(q * 128) * NC + cb + j;
        #pragma unroll
        for (int p = 0; p < 64; ++p) {
            v2h a, bzv, c;
            a[0]   = (_Float16)wb[0];        a[1]   = (_Float16)wb[NC];
            bzv[0] = (_Float16)wb[256];      bzv[1] = (_Float16)wb[NC + 256];
            c[0]   = (_Float16)wb[512];      c[1]   = (_Float16)wb[NC + 512];
            wr2[p] = a; wz2[p] = bzv; wn2[p] = c;
            wb += 2 * NC;
        }
    }
    const float br  = bhhc[cb + j];
    const float bzb = bhhc[cb + 256 + j];
    const float bnb = bhhc[cb + 512 + j];

    float hprev = 0.f;                      // q==0 thread j owns h[j]
    if (q == 0 && (j & 1) == 0) {
        v2h z0; z0[0] = (_Float16)0.f; z0[1] = (_Float16)0.f;
        h2s[j >> 1] = z0;
    }
    __syncthreads();

    const int t0i = dir ? (Tlen - 1) : 0;
    const long tstep = dir ? -1 : 1;
    const _Float16* girow = gi + (size_t)(b * Tlen + t0i) * NC + cb;
    _Float16* eptr = e + (size_t)(b * Tlen + t0i) * 512 + (dir << 8) + j;
    const long gstep = tstep * NC;
    const long estep = tstep * 512;

    _Float16* pptr = eptr;                  // pending e-store (delayed 1 step)
    float pval = 0.f;

    for (int s = 0; s < Tlen; ++s) {
        // delayed e-store + gi prefetch — both issue right after the barrier,
        // hidden under the dot loop; drained for free at the next barrier.
        float gr_ = 0.f, gz_ = 0.f, gn_ = 0.f;
        if (q == 0) {
            if (s > 0) *pptr = (_Float16)pval;
            gr_ = (float)girow[j];
            gz_ = (float)girow[256 + j];
            gn_ = (float)girow[512 + j];
        }

        float ar = 0.f, az = 0.f, an = 0.f;
        const v2h* hbase = &h2s[q * 64];
        #pragma unroll
        for (int c = 0; c < 16; ++c) {
            union { float4 f; v2h h[4]; } U;
            U.f = *(const float4*)&hbase[c * 4];
            #pragma unroll
            for (int p = 0; p < 4; ++p) {
                ar = FDOT2(wr2[c * 4 + p], U.h[p], ar);
                az = FDOT2(wz2[c * 4 + p], U.h[p], az);
                an = FDOT2(wn2[c * 4 + p], U.h[p], an);
            }
        }
        if (q == 1) { parts[0][j] = ar; parts[1][j] = az; parts[2][j] = an; }
        __syncthreads();                    // partials visible; all h2s reads done

        if (q == 0) {
            const float sr = ar + parts[0][j] + br;
            const float sz = az + parts[1][j] + bzb;
            const float sn = an + parts[2][j] + bnb;
            const float r = 1.f / (1.f + __expf(-(gr_ + sr)));
            const float z = 1.f / (1.f + __expf(-(gz_ + sz)));
            const float xa = gn_ + r * sn;
            const float texp = __expf(2.f * xa);
            const float n = 1.f - 2.f / (texp + 1.f);   // tanh(xa)
            const float hnew = (1.f - z) * n + z * hprev;
            hprev = hnew;
            pptr = eptr; pval = hnew;       // store deferred to next iteration
            const float hnb = __shfl_xor(hnew, 1);   // neighbor j^1 (same wave)
            if ((j & 1) == 0) {
                v2h hv; hv[0] = (_Float16)hnew; hv[1] = (_Float16)hnb;
                h2s[j >> 1] = hv;
            }
        }
        girow += gstep;
        eptr += estep;
        __syncthreads();                    // h2s updated before next reads
    }
    if (q == 0) *pptr = (_Float16)pval;     // flush final pending store
}

// ---------------------------------------------------------------------------
// K3: sim via f16 MFMA 16x16x32.  S[b,t,j] = sum_d (ctx*w2)[t,d]*ec[j,d] + act
// Per (seq,b): M=512(t) in 4 tiles of 128, N=128(j), K=512.
// A staged with w2 pre-scale (v_pk_mul_f16); fused rowmax in C-layout epilogue.
// ---------------------------------------------------------------------------
__global__ __launch_bounds__(256) void sim_mfma(
    const _Float16* __restrict__ e_src, const _Float16* __restrict__ e_tgt,
    const _Float16* __restrict__ e_cmnt, const _Float16* __restrict__ w2h,
    const float* __restrict__ w2,
    const int* __restrict__ src_action, const int* __restrict__ tgt_action,
    float* __restrict__ S, float* __restrict__ rowmaxP)
{
    const int sb = (int)blockIdx.z;          // seq*32 + b
    const int seq = sb >> 5, b = sb & 31;
    const int t0 = blockIdx.x * 128;
    const _Float16* ctx = ((seq == 0) ? e_src : e_tgt) + (size_t)b * 512 * 512;
    const _Float16* ec = e_cmnt + (size_t)b * 128 * 512;
    const int* act = (seq == 0) ? src_action : tgt_action;

    __shared__ __align__(16) _Float16 As[128 * LP];
    __shared__ __align__(16) _Float16 Bs[128 * LP];
    const int tid = threadIdx.x;
    const int wave = tid >> 6, lane = tid & 63;
    const int quad = lane >> 4, l16 = lane & 15;
    const int wm = (wave & 1) * 64, wn = (wave >> 1) * 64;
    const int sr = tid >> 2;            // 0..63
    const int sk = (tid & 3) * 8;       // 0,8,16,24

    const _Float16* ga0 = ctx + (size_t)(t0 + sr) * 512 + sk;
    const _Float16* ga1 = ctx + (size_t)(t0 + sr + 64) * 512 + sk;
    const _Float16* gb0 = ec + (size_t)sr * 512 + sk;
    const _Float16* gb1 = ec + (size_t)(sr + 64) * 512 + sk;

    f32x4 acc[4][4];
    #pragma unroll
    for (int i = 0; i < 4; ++i)
        #pragma unroll
        for (int j = 0; j < 4; ++j) acc[i][j] = (f32x4){0.f, 0.f, 0.f, 0.f};

    for (int k0 = 0; k0 < 512; k0 += 32) {
        v8h a0 = *(const v8h*)(ga0 + k0);
        v8h a1 = *(const v8h*)(ga1 + k0);
        const v8h b0 = *(const v8h*)(gb0 + k0);
        const v8h b1 = *(const v8h*)(gb1 + k0);
        const v8h w8 = *(const v8h*)(w2h + k0 + sk);
        a0 = a0 * w8;                                   // v_pk_mul_f16 x4
        a1 = a1 * w8;
        __syncthreads();
        *(v8h*)&As[sr * LP + sk] = a0;
        *(v8h*)&As[(sr + 64) * LP + sk] = a1;
        *(v8h*)&Bs[sr * LP + sk] = b0;
        *(v8h*)&Bs[(sr + 64) * LP + sk] = b1;
        __syncthreads();
        v8h af[4], bf[4];
        #pragma unroll
        for (int i = 0; i < 4; ++i)
            af[i] = *(const v8h*)&As[(wm + i * 16 + l16) * LP + quad * 8];
        #pragma unroll
        for (int j = 0; j < 4; ++j)
            bf[j] = *(const v8h*)&Bs[(wn + j * 16 + l16) * LP + quad * 8];
        #pragma unroll
        for (int i = 0; i < 4; ++i)
            #pragma unroll
            for (int j = 0; j < 4; ++j)
                acc[i][j] = __builtin_amdgcn_mfma_f32_16x16x32_f16(af[i], bf[j], acc[i][j], 0, 0, 0);
    }

    const float w2a = w2[512];
    #pragma unroll
    for (int i = 0; i < 4; ++i) {
        #pragma unroll
        for (int reg = 0; reg < 4; ++reg) {
            const int t = t0 + wm + i * 16 + quad * 4 + reg;
            const float aterm = (float)act[b * 512 + t] * w2a;
            float m = -1e30f;
            #pragma unroll
            for (int j = 0; j < 4; ++j) {
                const float v = acc[i][j][reg] + aterm;
                S[((size_t)(sb * 512 + t)) * 128 + wn + j * 16 + l16] = v;
                m = fmaxf(m, v);
            }
            m = fmaxf(m, __shfl_xor(m, 1));
            m = fmaxf(m, __shfl_xor(m, 2));
            m = fmaxf(m, __shfl_xor(m, 4));
            m = fmaxf(m, __shfl_xor(m, 8));
            if (l16 == 0)
                rowmaxP[(size_t)(wave >> 1) * 32768 + sb * 512 + t] = m;
        }
    }
}

// K5: softmax over t (512) per (seq,b); combines the 2 j-tile max partials
__global__ __launch_bounds__(256) void softmax_kernel(const float* __restrict__ rowmaxP, float* __restrict__ bw)
{
    const int base = blockIdx.x * 512;
    const int tid = threadIdx.x;
    __shared__ float red[256];
    const float v0 = fmaxf(rowmaxP[base + tid], rowmaxP[32768 + base + tid]);
    const float v1 = fmaxf(rowmaxP[base + 256 + tid], rowmaxP[32768 + base + 256 + tid]);
    red[tid] = fmaxf(v0, v1);
    __syncthreads();
    for (int off = 128; off > 0; off >>= 1) {
        if (tid < off) red[tid] = fmaxf(red[tid], red[tid + off]);
        __syncthreads();
    }
    const float M = red[0];
    __syncthreads();
    const float e0 = __expf(v0 - M), e1 = __expf(v1 - M);
    red[tid] = e0 + e1;
    __syncthreads();
    for (int off = 128; off > 0; off >>= 1) {
        if (tid < off) red[tid] += red[tid + off];
        __syncthreads();
    }
    const float inv = 1.f / red[0];
    bw[base + tid] = e0 * inv;
    bw[base + 256 + tid] = e1 * inv;
}

// K6: outSP[c][sb*128+j] = sum_{t in chunk c} bw[sb,t] * S[sb,t,j]
__global__ __launch_bounds__(256) void weighted_kernel(
    const float* __restrict__ S, const float* __restrict__ bw, float* __restrict__ outSP)
{
    const int sb = blockIdx.x;          // seq*32 + b
    const int ch = blockIdx.y;          // t-chunk 0..7
    const int tid = threadIdx.x;
    const int j = tid & 127, half = tid >> 7;
    const float* Sb = S + (size_t)sb * 512 * 128;
    const float* w = bw + sb * 512;
    const int tb = ch * 64 + half * 32;
    float acc = 0.f;
    for (int t = tb; t < tb + 32; ++t)
        acc = fmaf(w[t], Sb[(size_t)t * 128 + j], acc);
    __shared__ float red[256];
    red[tid] = acc;
    __syncthreads();
    if (half == 0) outSP[(size_t)ch * 8192 + sb * 128 + j] = red[j] + red[128 + j];
}

// K7: sum chunk partials; write S_diff and result into d_out
__global__ __launch_bounds__(256) void final_kernel(
    const float* __restrict__ outSP, const float* __restrict__ rank_w,
    const float* __restrict__ rank_b, float* __restrict__ out)
{
    __shared__ float sArr[8192];
    const int tid = threadIdx.x;
    for (int q = tid; q < 8192; q += 256) {
        float s = 0.f;
        #pragma unroll
        for (int c = 0; c < 8; ++c) s += outSP[(size_t)c * 8192 + q];
        sArr[q] = s;
    }
    __syncthreads();
    for (int q = tid; q < 8192; q += 256) {
        const int b = q >> 8, c = q & 255;
        out[32 + q] = (c < 128) ? sArr[b * 128 + c] : sArr[4096 + b * 128 + (c - 128)];
    }
    if (tid < 32) {
        float acc = rank_b[0];
        for (int c = 0; c < 128; ++c) acc = fmaf(sArr[tid * 128 + c], rank_w[c], acc);
        for (int c = 0; c < 128; ++c) acc = fmaf(sArr[4096 + tid * 128 + c], rank_w[128 + c], acc);
        out[tid] = acc;
    }
}

// ---------------------------------------------------------------------------
extern "C" void kernel_launch(void* const* d_in, const int* in_sizes, int n_in,
                              void* d_out, int out_size, void* d_ws, size_t ws_size,
                              hipStream_t stream)
{
    const int* cmnt       = (const int*)d_in[0];
    const int* src_token  = (const int*)d_in[1];
    const int* tgt_token  = (const int*)d_in[2];
    const int* src_action = (const int*)d_in[3];
    const int* tgt_action = (const int*)d_in[4];
    const float* emb    = (const float*)d_in[5];
    const float* wih_f  = (const float*)d_in[6];
    const float* whh_f  = (const float*)d_in[7];
    const float* bih_f  = (const float*)d_in[8];
    const float* bhh_f  = (const float*)d_in[9];
    const float* wih_b  = (const float*)d_in[10];
    const float* whh_b  = (const float*)d_in[11];
    const float* bih_b  = (const float*)d_in[12];
    const float* bhh_b  = (const float*)d_in[13];
    const float* w2     = (const float*)d_in[14];
    const float* rank_w = (const float*)d_in[15];
    const float* rank_b = (const float*)d_in[16];
    float* out = (float*)d_out;

    // Workspace layout (units: fp32 slots). e_* and gi are fp16.
    float* ws = (float*)d_ws;
    size_t off = 0;
    int*   tok_all = (int*)(ws + off); off += 36864;
    short* Bt_bf16 = (short*)(ws + off); off += 196608;       // 1536x256 bf16
    float* whhT   = ws + off; off += 393216;
    float* bihc   = ws + off; off += 1536;
    float* bhhc   = ws + off; off += 1536;
    _Float16* w2h = (_Float16*)(ws + off); off += 256;        // 512 halfs
    float* rowmaxP = ws + off; off += 65536;                  // 2 x 32768
    float* bw     = ws + off; off += 32768;
    float* outSP  = ws + off; off += 65536;                   // 8 x 8192
    _Float16* e_src  = (_Float16*)(ws + off); off += 4194304; // 8.4M halfs
    _Float16* e_tgt  = (_Float16*)(ws + off); off += 4194304;
    _Float16* e_cmnt = (_Float16*)(ws + off); off += 1048576; // 2.1M halfs
    float* S      = ws + off; off += 4194304;
    _Float16* gih = (_Float16*)(ws + off);
    const size_t avail = ws_size / 4 - off;
    // Tier A: full fp16 gi (36864 x 1536 halfs = 28311552 fp32 slots)
    const bool planP = avail >= 28311552ULL;

    hipLaunchKernelGGL(prep_kernel, dim3(512), dim3(256), 0, stream,
        cmnt, src_token, tgt_token, wih_f, wih_b, whh_f, whh_b,
        bih_f, bih_b, bhh_f, bhh_b, w2, tok_all, whhT, bihc, bhhc, Bt_bf16, w2h);

    if (planP) {
        // A_bf16 (36864x256 shorts) aliases e_src+e_tgt, consumed before gru writes e.
        short* A = (short*)e_src;
        hipLaunchKernelGGL(gatherA_kernel, dim3(4096), dim3(256), 0, stream,
            tok_all, 0, 36864, emb, A);
        hipLaunchKernelGGL(gi_mfma, dim3(288, 12), dim3(256), 0, stream,
            A, Bt_bf16, bihc, gih);
        hipLaunchKernelGGL(gru_kernel, dim3(192), dim3(512), 0, stream,
            gih, gih + (size_t)16384 * NC, gih + (size_t)32768 * NC,
            whhT, bhhc, e_src, e_tgt, e_cmnt, 0);
    } else {
        // Serial fallback: per-seq fp16 gi chunk; A aliases S
        short* A = (short*)S;
        const int starts[3] = {0, 16384, 32768};
        const int nrows[3]  = {16384, 16384, 4096};
        for (int sq = 0; sq < 3; ++sq) {
            hipLaunchKernelGGL(gatherA_kernel, dim3(4096), dim3(256), 0, stream,
                tok_all, starts[sq], nrows[sq], emb, A);
            hipLaunchKernelGGL(gi_mfma, dim3(nrows[sq] / 128, 12), dim3(256), 0, stream,
                A, Bt_bf16, bihc, gih);
            hipLaunchKernelGGL(gru_kernel, dim3(64), dim3(512), 0, stream,
                gih, gih, gih, whhT, bhhc, e_src, e_tgt, e_cmnt, 2 * sq);
        }
    }

    hipLaunchKernelGGL(sim_mfma, dim3(4, 1, 64), dim3(256), 0, stream,
        e_src, e_tgt, e_cmnt, w2h, w2, src_action, tgt_action, S, rowmaxP);
    hipLaunchKernelGGL(softmax_kernel, dim3(64), dim3(256), 0, stream, rowmaxP, bw);
    hipLaunchKernelGGL(weighted_kernel, dim3(64, 8), dim3(256), 0, stream, S, bw, outSP);
    hipLaunchKernelGGL(final_kernel, dim3(1), dim3(256), 0, stream, outSP, rank_w, rank_b, out);
}